// Round 1
// baseline (345.578 us; speedup 1.0000x reference)
//
#include <hip/hip_runtime.h>
#include <hip/hip_bf16.h>

// DenoisingPotential: x_{t+1} = x_t + alpha * grad_phi(x_t), 10 iters.
// grad = (pacc - sum_k w_k y_k)/l,  y_k = P_k x,  w_k = exp(e_k + Pmu_k.x - 0.5 x.y_k)
//
// R4: k-split across wave pairs. Waves (2w, 2w+1) share 32 points; wave khalf
// owns clusters [khalf*16, khalf*16+16). Partial accY / lsum / weights are
// exchanged through LDS once per outer iteration (2 barriers/iter). Grid
// doubles to 1024 -> 4 blocks/CU; per-wave L2 traffic for P halves, so total
// L2 traffic is unchanged. Also: 4-accumulator dot (breaks the 16-deep serial
// FMA chain), ds_swizzle+permlane32_swap reduction (1 DS op instead of 2),
// e_k folded into staged pmx, weight-stash pitch padded 32->40 bf16.

typedef __attribute__((ext_vector_type(4))) float f32x4;
typedef __attribute__((ext_vector_type(8))) short bf16x8;  // 8 bf16 = 4 VGPRs

#define KC 32
#define KH 16          // clusters per wave (k-split)
#define NITER 10
#define XROW 72        // bf16 elems per point-row in xs staging (pad vs 64)
#define PW_BYTES 8704  // per-wave region: xsw(4608)->pmxw(2048)->exw(8704)
#define WT_PITCH 40    // bf16 pitch of weight stash (pad vs 32: kills 16-way conflict)
#define WT_BYTES 2560  // 32 pts * 40 * 2B, shared per pair
#define LS_BYTES 256   // per-pair lsum exchange: 2 waves * 32 pts * f32
// LDS total: 4*8704 + 2*2560 + 2*256 = 40448 B -> 4 blocks/CU

static __device__ __forceinline__ unsigned pk_bf16(float a, float b) {
  __hip_bfloat16 ha = __float2bfloat16(a), hb = __float2bfloat16(b);
  unsigned short ua = *(unsigned short*)&ha, ub = *(unsigned short*)&hb;
  return (unsigned)ua | ((unsigned)ub << 16);
}

// butterfly sum with lane^16 (ds_swizzle xor-16, BitMode offset 0x401F)
static __device__ __forceinline__ float red16(float x) {
  int v = __builtin_amdgcn_ds_swizzle(__float_as_int(x), 0x401F);
  return x + __int_as_float(v);
}
// butterfly sum with lane^32 (VALU permlane32_swap: both outputs summed give
// x[i] + x[i^32] in every lane)
static __device__ __forceinline__ float red32(float x) {
  int xi = __float_as_int(x);
  auto pr = __builtin_amdgcn_permlane32_swap(xi, xi, false, false);
  return __int_as_float(pr[0]) + __int_as_float(pr[1]);
}

// ---------------- precompute 1: per-k P = A^T A, Pmu, e, swizzled P ----------
// A staged in LDS; each thread owns (i, 16-col strip) -> all LDS reads are
// broadcasts / b128; Pmu via symmetric transposed read (conflict-free);
// e via wave-parallel reduce; Psw stores packed 2xbf16.
__global__ void precompute1(const float* __restrict__ A, const float* __restrict__ mu,
                            const float* __restrict__ c,
                            float* __restrict__ Pmu_g, float* __restrict__ e_g,
                            __hip_bfloat16* __restrict__ Psw) {
  __shared__ float As[64 * 64];
  __shared__ float Pk[64 * 64];
  const int k = blockIdx.x, tid = threadIdx.x;
  const float* Ak = A + k * 4096;
  for (int idx = tid; idx < 1024; idx += 256)
    *(f32x4*)&As[idx * 4] = *(const f32x4*)&Ak[idx * 4];
  __syncthreads();

  // thread -> row i = tid>>2, col strip lg*16..lg*16+15
  const int i = tid >> 2, lg = tid & 3;
  float acc[16] = {};
  for (int j = 0; j < 64; ++j) {
    float ai = As[j * 64 + i];  // broadcast within quad
    const f32x4* row = (const f32x4*)&As[j * 64 + lg * 16];  // broadcast across i
#pragma unroll
    for (int g = 0; g < 4; ++g) {
      f32x4 v = row[g];
#pragma unroll
      for (int r = 0; r < 4; ++r) acc[g * 4 + r] += ai * v[r];
    }
  }
#pragma unroll
  for (int g = 0; g < 4; ++g)
#pragma unroll
    for (int r = 0; r < 4; ++r) Pk[i * 64 + lg * 16 + g * 4 + r] = acc[g * 4 + r];
  __syncthreads();

  if (tid < 64) {
    // Pmu[i] = sum_l P[l][i]*mu[l]  (P symmetric; transposed read = stride-1)
    float s = 0.f;
    for (int l = 0; l < 64; ++l) s += Pk[l * 64 + tid] * mu[k * 64 + l];
    Pmu_g[k * 64 + tid] = s;
    float v = mu[k * 64 + tid] * s;
#pragma unroll
    for (int off = 1; off < 64; off <<= 1) v += __shfl_xor(v, off, 64);
    if (tid == 0) e_g[k] = c[k] - 0.5f * v;
  }

  // A-frag order for the main GEMM: flat idx = f*512 + lane*8 + j,
  // f=(mt,s): val = P[dim_in = s*32 + qq*8 + j][dim_out = mt*16 + l4]
  unsigned* Psw32 = (unsigned*)(Psw + k * 4096);
  for (int idx2 = tid; idx2 < 2048; idx2 += 256) {
    int idx = idx2 << 1;  // even j
    int f = idx >> 9, ln = (idx >> 3) & 63, j = idx & 7;
    int mt = f >> 1, s = f & 1, qq = ln >> 4, l4 = ln & 15;
    int col = mt * 16 + l4, rb = s * 32 + qq * 8 + j;
    Psw32[idx2] = pk_bf16(Pk[rb * 64 + col], Pk[(rb + 1) * 64 + col]);
  }
}

// ---------------- precompute 2: Pmu fragment swizzles -----------------------
__global__ void precompute2(const float* __restrict__ Pmu_g,
                            __hip_bfloat16* __restrict__ PmuA,
                            __hip_bfloat16* __restrict__ PmuB) {
  const int tid = threadIdx.x;
  // PmuA (pmx GEMM A-operand): A[m=cluster][kk=dim]; frag f=(mtc,s)
  for (int idx = tid; idx < 2048; idx += 256) {
    int f = idx >> 9, lane = (idx >> 3) & 63, j = idx & 7;
    int mtc = f >> 1, s = f & 1, qq = lane >> 4, l4 = lane & 15;
    PmuA[idx] = __float2bfloat16(Pmu_g[(mtc * 16 + l4) * 64 + s * 32 + qq * 8 + j]);
  }
  // PmuB (pacc GEMM A-operand): A[m=dim][kk=cluster]; frag f=mtd (K=32, 1 step)
  for (int idx = tid; idx < 2048; idx += 256) {
    int f = idx >> 9, lane = (idx >> 3) & 63, j = idx & 7;
    int qq = lane >> 4, l4 = lane & 15;
    PmuB[idx] = __float2bfloat16(Pmu_g[(qq * 8 + j) * 64 + f * 16 + l4]);
  }
}

// ---------------- main kernel ----------------------------------------------
// 256 thr (4 waves = 2 pairs), 64 pts/block, grid 1024. Wave pair shares 32
// points; wave khalf owns clusters [khalf*16, +16). Two __syncthreads/iter.
__launch_bounds__(256, 2)
__global__ void denoise_main(const float* __restrict__ x_in,
                             const float* __restrict__ e_g,
                             const float* __restrict__ alpha_g,
                             const __hip_bfloat16* __restrict__ Psw,
                             const __hip_bfloat16* __restrict__ PmuA,
                             const __hip_bfloat16* __restrict__ PmuB,
                             float* __restrict__ out) {
  __shared__ __attribute__((aligned(16))) char scratch[4 * PW_BYTES + 2 * WT_BYTES + 2 * LS_BYTES];

  const int tid = threadIdx.x;
  const int wave = tid >> 6, lane = tid & 63;
  const int pair = wave >> 1, khalf = wave & 1;
  const int q = lane >> 4, l4 = lane & 15;
  const int base_pt = blockIdx.x * 64 + pair * 32;
  const float alpha = alpha_g[0];
  const int kbase = khalf * KH;

  char* pw = scratch + wave * PW_BYTES;
  __hip_bfloat16* xsw = (__hip_bfloat16*)pw;  // [32][XROW] bf16 (staging)
  float* pmxw = (float*)pw;                   // [16][32] f32 (xsw dead by then)
  float* exw = (float*)pw;                    // [32][68] f32 accY exchange (pmxw dead)
  const float* exw_p = (const float*)(scratch + (wave ^ 1) * PW_BYTES);
  __hip_bfloat16* wtw = (__hip_bfloat16*)(scratch + 4 * PW_BYTES + pair * WT_BYTES);
  float* lsw = (float*)(scratch + 4 * PW_BYTES + 2 * WT_BYTES + pair * LS_BYTES);

  const bf16x8* PswF = (const bf16x8*)Psw;    // frag idx = k*512 + f*64 + lane
  const bf16x8* PmuAF = (const bf16x8*)PmuA;  // frag idx = f*64 + lane
  const bf16x8* PmuBF = (const bf16x8*)PmuB;

  // x master, C-layout: xm[mt][nt][r] = x[dim = mt*16+q*4+r][pt = nt*16+l4]
  f32x4 xm[4][2];
#pragma unroll
  for (int mt = 0; mt < 4; ++mt)
#pragma unroll
    for (int nt = 0; nt < 2; ++nt)
      xm[mt][nt] = *(const f32x4*)&x_in[(base_pt + nt * 16 + l4) * 64 + mt * 16 + q * 4];

  // e for this wave's clusters: spill row q*4+r -> cluster kbase+q*4+r
  const f32x4 ev = *(const f32x4*)&e_g[kbase + q * 4];

  const f32x4 Z4 = {0.f, 0.f, 0.f, 0.f};

#pragma unroll 1
  for (int it = 0; it < NITER; ++it) {
    // ---- stage x (bf16) into wave-private rows [pt][dim], XROW-padded ----
#pragma unroll
    for (int mt = 0; mt < 4; ++mt)
#pragma unroll
      for (int nt = 0; nt < 2; ++nt) {
        uint2 v;
        v.x = pk_bf16(xm[mt][nt][0], xm[mt][nt][1]);
        v.y = pk_bf16(xm[mt][nt][2], xm[mt][nt][3]);
        *(uint2*)&xsw[(nt * 16 + l4) * XROW + mt * 16 + q * 4] = v;
      }

    // ---- B-frags of x: B[kk=dim=s*32+q*8+j][n=pt=l4] (constant over k) ----
    bf16x8 bx[2][2];
#pragma unroll
    for (int s = 0; s < 2; ++s)
#pragma unroll
      for (int nt = 0; nt < 2; ++nt)
        bx[s][nt] = *(const bf16x8*)&xsw[(nt * 16 + l4) * XROW + s * 32 + q * 8];

    // ---- preload P(k=kbase) fragments into register buffer 0 ----
    bf16x8 ap[2][4][2];
#pragma unroll
    for (int mt = 0; mt < 4; ++mt)
#pragma unroll
      for (int s = 0; s < 2; ++s)
        ap[0][mt][s] = PswF[kbase * 512 + (mt * 2 + s) * 64 + lane];

    // ---- pmx GEMM (own cluster tile only): pmx[cluster][pt] ----
    f32x4 pmx[2];
#pragma unroll
    for (int nt = 0; nt < 2; ++nt) {
      f32x4 acc = Z4;
#pragma unroll
      for (int s = 0; s < 2; ++s) {
        bf16x8 a = PmuAF[(khalf * 2 + s) * 64 + lane];
        acc = __builtin_amdgcn_mfma_f32_16x16x32_bf16(a, bx[s][nt], acc, 0, 0, 0);
      }
      pmx[nt] = acc;
    }
    // spill pmx + e (folded) to wave-private LDS [cluster16][pt32]
#pragma unroll
    for (int nt = 0; nt < 2; ++nt)
#pragma unroll
      for (int r = 0; r < 4; ++r)
        pmxw[(q * 4 + r) * 32 + nt * 16 + l4] = pmx[nt][r] + ev[r];

    f32x4 accY[4][2];
#pragma unroll
    for (int mt = 0; mt < 4; ++mt)
#pragma unroll
      for (int nt = 0; nt < 2; ++nt) accY[mt][nt] = Z4;
    float lsum0 = 0.f, lsum1 = 0.f;

    // ---- k-loop over own 16 clusters: register-double-buffered P ----
#pragma unroll 2
    for (int kk = 0; kk < KH; ++kk) {
      const int cur = kk & 1, nxt = cur ^ 1;
      const int kn = kbase + ((kk + 1) & (KH - 1));  // wraps within own half
#pragma unroll
      for (int mt = 0; mt < 4; ++mt)
#pragma unroll
        for (int s = 0; s < 2; ++s)
          ap[nxt][mt][s] = PswF[kn * 512 + (mt * 2 + s) * 64 + lane];

      // y = P x : C[row=dim=mt*16+q*4+r][col=pt=nt*16+l4]
      f32x4 y[4][2];
#pragma unroll
      for (int mt = 0; mt < 4; ++mt)
#pragma unroll
        for (int nt = 0; nt < 2; ++nt) {
          f32x4 acc = Z4;
          acc = __builtin_amdgcn_mfma_f32_16x16x32_bf16(ap[cur][mt][0], bx[0][nt], acc, 0, 0, 0);
          acc = __builtin_amdgcn_mfma_f32_16x16x32_bf16(ap[cur][mt][1], bx[1][nt], acc, 0, 0, 0);
          y[mt][nt] = acc;
        }

      // xy[pt] = x . y : 4 parallel accumulators (chain depth 4, not 16)
      f32x4 d0 = xm[0][0] * y[0][0];
      f32x4 d1 = xm[0][1] * y[0][1];
#pragma unroll
      for (int mt = 1; mt < 4; ++mt) {
        d0 += xm[mt][0] * y[mt][0];
        d1 += xm[mt][1] * y[mt][1];
      }
      float xy0 = (d0[0] + d0[1]) + (d0[2] + d0[3]);
      float xy1 = (d1[0] + d1[1]) + (d1[2] + d1[3]);
      xy0 = red32(red16(xy0));
      xy1 = red32(red16(xy1));

      const float pk0 = pmxw[kk * 32 + l4];       // includes e_k
      const float pk1 = pmxw[kk * 32 + 16 + l4];
      const float w0 = __expf(pk0 - 0.5f * xy0);
      const float w1 = __expf(pk1 - 0.5f * xy1);
      lsum0 += w0;
      lsum1 += w1;
      if (q == 0) {
        wtw[l4 * WT_PITCH + kbase + kk] = __float2bfloat16(w0);
        wtw[(16 + l4) * WT_PITCH + kbase + kk] = __float2bfloat16(w1);
      }
#pragma unroll
      for (int mt = 0; mt < 4; ++mt) {
        accY[mt][0] += w0 * y[mt][0];
        accY[mt][1] += w1 * y[mt][1];
      }
    }

    // ---- exchange partials with pair partner (f32, own region; pmxw dead) --
#pragma unroll
    for (int mt = 0; mt < 4; ++mt)
#pragma unroll
      for (int nt = 0; nt < 2; ++nt)
        *(f32x4*)&exw[(nt * 16 + l4) * 68 + mt * 16 + q * 4] = accY[mt][nt];
    if (q == 0) {
      lsw[khalf * 32 + l4] = lsum0;
      lsw[khalf * 32 + 16 + l4] = lsum1;
    }
    __syncthreads();

#pragma unroll
    for (int mt = 0; mt < 4; ++mt)
#pragma unroll
      for (int nt = 0; nt < 2; ++nt)
        accY[mt][nt] += *(const f32x4*)&exw_p[(nt * 16 + l4) * 68 + mt * 16 + q * 4];
    const float lt0 = lsum0 + lsw[(khalf ^ 1) * 32 + l4];
    const float lt1 = lsum1 + lsw[(khalf ^ 1) * 32 + 16 + l4];

    // ---- pacc[dim][pt] = sum_k Pmu[k][dim] * wt[k][pt] (full K=32 GEMM) ----
    bf16x8 wtf[2];
#pragma unroll
    for (int nt = 0; nt < 2; ++nt)
      wtf[nt] = *(const bf16x8*)&wtw[(nt * 16 + l4) * WT_PITCH + q * 8];
    f32x4 pacc[4][2];
#pragma unroll
    for (int mt = 0; mt < 4; ++mt) {
      bf16x8 a = PmuBF[mt * 64 + lane];
      pacc[mt][0] = __builtin_amdgcn_mfma_f32_16x16x32_bf16(a, wtf[0], Z4, 0, 0, 0);
      pacc[mt][1] = __builtin_amdgcn_mfma_f32_16x16x32_bf16(a, wtf[1], Z4, 0, 0, 0);
    }

    // ---- x += (alpha/l) * (pacc - accY); both waves compute identical xm ----
    const float c0 = alpha / lt0;
    const float c1 = alpha / lt1;
#pragma unroll
    for (int mt = 0; mt < 4; ++mt) {
      xm[mt][0] += c0 * (pacc[mt][0] - accY[mt][0]);
      xm[mt][1] += c1 * (pacc[mt][1] - accY[mt][1]);
    }
    __syncthreads();  // protect exw/wtw/lsw before next iteration overwrites
  }  // iterations

  // ---- output: wave writes dims [khalf*32, +32) for its pair's 32 points ---
  // per (l4): the 4 q-lanes fill one 64B line -> fully coalesced 16B stores
#pragma unroll
  for (int mt2 = 0; mt2 < 2; ++mt2)
#pragma unroll
    for (int nt = 0; nt < 2; ++nt)
      *(f32x4*)&out[(base_pt + nt * 16 + l4) * 64 + khalf * 32 + mt2 * 16 + q * 4] =
          xm[khalf * 2 + mt2][nt];
}

extern "C" void kernel_launch(void* const* d_in, const int* in_sizes, int n_in,
                              void* d_out, int out_size, void* d_ws, size_t ws_size,
                              hipStream_t stream) {
  (void)in_sizes; (void)n_in; (void)out_size; (void)ws_size;
  const float* x = (const float*)d_in[0];
  const float* c = (const float*)d_in[1];
  const float* mu = (const float*)d_in[2];
  const float* A = (const float*)d_in[3];
  const float* alpha = (const float*)d_in[4];
  float* out = (float*)d_out;

  char* ws = (char*)d_ws;
  float* Pmu_g = (float*)(ws);                           // 8192 B
  float* e_g = (float*)(ws + 8192);                      // 128 B (pad to 256)
  __hip_bfloat16* PmuA = (__hip_bfloat16*)(ws + 8448);   // 4096 B
  __hip_bfloat16* PmuB = (__hip_bfloat16*)(ws + 12544);  // 4096 B
  __hip_bfloat16* Psw = (__hip_bfloat16*)(ws + 16640);   // 262144 B

  precompute1<<<32, 256, 0, stream>>>(A, mu, c, Pmu_g, e_g, Psw);
  precompute2<<<1, 256, 0, stream>>>(Pmu_g, PmuA, PmuB);
  denoise_main<<<1024, 256, 0, stream>>>(x, e_g, alpha, Psw, PmuA, PmuB, out);
}

// Round 2
// 290.512 us; speedup vs baseline: 1.1895x; 1.1895x over previous
//
#include <hip/hip_runtime.h>
#include <hip/hip_bf16.h>

// DenoisingPotential: x_{t+1} = x_t + alpha * grad_phi(x_t), 10 iters.
// grad = (pacc - sum_k w_k y_k)/l,  y_k = P_k x,  w_k = exp(e_k + Pmu_k.x - 0.5 x.y_k)
//
// R5: revert R4's k-split (it spilled ~320 MB of scratch traffic and never
// raised residency; barriers + pair-exchange live-set blew the 128-VGPR
// budget). Back to R3's barrier-free wave-private structure (grid 512,
// 32 pts/wave, full K=32 per wave), plus VALU-side cuts:
//   - dot / accY / xm-update as f32x4 vector exprs -> packed v_pk_fma_f32
//   - reduce via ds_swizzle(xor16) + permlane32_swap(xor32) (1 DS op, 1 VALU)
//   - e_k folded into staged pmx (no per-k global load)
//   - weight-stash pitch 40 bf16 (kills the 16-way bank conflict)
//   - direct f32x4 output stores; R4's faster precompute1 kept

typedef __attribute__((ext_vector_type(4))) float f32x4;
typedef __attribute__((ext_vector_type(8))) short bf16x8;  // 8 bf16 = 4 VGPRs

#define KC 32
#define NITER 10
#define XROW 72        // bf16 elems per point-row in xs staging (pad vs 64)
#define WT_PITCH 40    // bf16 pitch of weight stash (pad vs 32)
#define PW_BYTES 7168  // per-wave: xsw(4608, aliased by pmxw 4096) + wtw(2560)
// LDS total: 4 * 7168 = 28672 B

static __device__ __forceinline__ unsigned pk_bf16(float a, float b) {
  __hip_bfloat16 ha = __float2bfloat16(a), hb = __float2bfloat16(b);
  unsigned short ua = *(unsigned short*)&ha, ub = *(unsigned short*)&hb;
  return (unsigned)ua | ((unsigned)ub << 16);
}

// butterfly sum with lane^16 (ds_swizzle xor-16, BitMode offset 0x401F)
static __device__ __forceinline__ float red16(float x) {
  int v = __builtin_amdgcn_ds_swizzle(__float_as_int(x), 0x401F);
  return x + __int_as_float(v);
}
// butterfly sum with lane^32 (VALU permlane32_swap; sum of both outputs
// gives x[i] + x[i^32] in every lane)
static __device__ __forceinline__ float red32(float x) {
  int xi = __float_as_int(x);
  auto pr = __builtin_amdgcn_permlane32_swap(xi, xi, false, false);
  return __int_as_float(pr[0]) + __int_as_float(pr[1]);
}

// ---------------- precompute 1: per-k P = A^T A, Pmu, e, swizzled P ----------
__global__ void precompute1(const float* __restrict__ A, const float* __restrict__ mu,
                            const float* __restrict__ c,
                            float* __restrict__ Pmu_g, float* __restrict__ e_g,
                            __hip_bfloat16* __restrict__ Psw) {
  __shared__ float As[64 * 64];
  __shared__ float Pk[64 * 64];
  const int k = blockIdx.x, tid = threadIdx.x;
  const float* Ak = A + k * 4096;
  for (int idx = tid; idx < 1024; idx += 256)
    *(f32x4*)&As[idx * 4] = *(const f32x4*)&Ak[idx * 4];
  __syncthreads();

  // thread -> row i = tid>>2, col strip lg*16..lg*16+15
  const int i = tid >> 2, lg = tid & 3;
  float acc[16] = {};
  for (int j = 0; j < 64; ++j) {
    float ai = As[j * 64 + i];  // broadcast within quad
    const f32x4* row = (const f32x4*)&As[j * 64 + lg * 16];  // broadcast across i
#pragma unroll
    for (int g = 0; g < 4; ++g) {
      f32x4 v = row[g];
#pragma unroll
      for (int r = 0; r < 4; ++r) acc[g * 4 + r] += ai * v[r];
    }
  }
#pragma unroll
  for (int g = 0; g < 4; ++g)
#pragma unroll
    for (int r = 0; r < 4; ++r) Pk[i * 64 + lg * 16 + g * 4 + r] = acc[g * 4 + r];
  __syncthreads();

  if (tid < 64) {
    // Pmu[i] = sum_l P[l][i]*mu[l]  (P symmetric; transposed read = stride-1)
    float s = 0.f;
    for (int l = 0; l < 64; ++l) s += Pk[l * 64 + tid] * mu[k * 64 + l];
    Pmu_g[k * 64 + tid] = s;
    float v = mu[k * 64 + tid] * s;
#pragma unroll
    for (int off = 1; off < 64; off <<= 1) v += __shfl_xor(v, off, 64);
    if (tid == 0) e_g[k] = c[k] - 0.5f * v;
  }

  // A-frag order for the main GEMM: flat idx = f*512 + lane*8 + j,
  // f=(mt,s): val = P[dim_in = s*32 + qq*8 + j][dim_out = mt*16 + l4]
  unsigned* Psw32 = (unsigned*)(Psw + k * 4096);
  for (int idx2 = tid; idx2 < 2048; idx2 += 256) {
    int idx = idx2 << 1;  // even j
    int f = idx >> 9, ln = (idx >> 3) & 63, j = idx & 7;
    int mt = f >> 1, s = f & 1, qq = ln >> 4, l4 = ln & 15;
    int col = mt * 16 + l4, rb = s * 32 + qq * 8 + j;
    Psw32[idx2] = pk_bf16(Pk[rb * 64 + col], Pk[(rb + 1) * 64 + col]);
  }
}

// ---------------- precompute 2: Pmu fragment swizzles -----------------------
__global__ void precompute2(const float* __restrict__ Pmu_g,
                            __hip_bfloat16* __restrict__ PmuA,
                            __hip_bfloat16* __restrict__ PmuB) {
  const int tid = threadIdx.x;
  // PmuA (pmx GEMM A-operand): A[m=cluster][kk=dim]; frag f=(mtc,s)
  for (int idx = tid; idx < 2048; idx += 256) {
    int f = idx >> 9, lane = (idx >> 3) & 63, j = idx & 7;
    int mtc = f >> 1, s = f & 1, qq = lane >> 4, l4 = lane & 15;
    PmuA[idx] = __float2bfloat16(Pmu_g[(mtc * 16 + l4) * 64 + s * 32 + qq * 8 + j]);
  }
  // PmuB (pacc GEMM A-operand): A[m=dim][kk=cluster]; frag f=mtd (K=32, 1 step)
  for (int idx = tid; idx < 2048; idx += 256) {
    int f = idx >> 9, lane = (idx >> 3) & 63, j = idx & 7;
    int qq = lane >> 4, l4 = lane & 15;
    PmuB[idx] = __float2bfloat16(Pmu_g[(qq * 8 + j) * 64 + f * 16 + l4]);
  }
}

// ---------------- main kernel ----------------------------------------------
// 256 thr (4 waves), 32 pts/wave, grid 512. NO __syncthreads anywhere; all
// LDS use is wave-private scratch. P comes via register double-buffer.
__launch_bounds__(256, 2)
__global__ void denoise_main(const float* __restrict__ x_in,
                             const float* __restrict__ e_g,
                             const float* __restrict__ alpha_g,
                             const __hip_bfloat16* __restrict__ Psw,
                             const __hip_bfloat16* __restrict__ PmuA,
                             const __hip_bfloat16* __restrict__ PmuB,
                             float* __restrict__ out) {
  __shared__ __attribute__((aligned(16))) char scratch[4 * PW_BYTES];  // 28 KB

  const int tid = threadIdx.x;
  const int wave = tid >> 6, lane = tid & 63;
  const int q = lane >> 4, l4 = lane & 15;
  const int base_pt = blockIdx.x * 128 + wave * 32;
  const float alpha = alpha_g[0];

  char* pw = scratch + wave * PW_BYTES;
  __hip_bfloat16* xsw = (__hip_bfloat16*)pw;           // [32][XROW] bf16 staging
  float* pmxw = (float*)pw;                            // [32][32] f32 (xsw dead)
  __hip_bfloat16* wtw = (__hip_bfloat16*)(pw + 4608);  // [32][WT_PITCH] bf16

  const bf16x8* PswF = (const bf16x8*)Psw;    // frag idx = k*512 + f*64 + lane
  const bf16x8* PmuAF = (const bf16x8*)PmuA;  // frag idx = f*64 + lane
  const bf16x8* PmuBF = (const bf16x8*)PmuB;

  // x master, C-layout: xm[mt][nt][r] = x[dim = mt*16+q*4+r][pt = nt*16+l4]
  f32x4 xm[4][2];
#pragma unroll
  for (int mt = 0; mt < 4; ++mt)
#pragma unroll
    for (int nt = 0; nt < 2; ++nt)
      xm[mt][nt] = *(const f32x4*)&x_in[(base_pt + nt * 16 + l4) * 64 + mt * 16 + q * 4];

  // e for pmx spill: cluster row mtc*16 + q*4 + r  ->  ev[mtc][r]
  f32x4 ev[2];
#pragma unroll
  for (int mtc = 0; mtc < 2; ++mtc) ev[mtc] = *(const f32x4*)&e_g[mtc * 16 + q * 4];

  const f32x4 Z4 = {0.f, 0.f, 0.f, 0.f};

#pragma unroll 1
  for (int it = 0; it < NITER; ++it) {
    // ---- stage x (bf16) into wave-private rows [pt][dim], XROW-padded ----
#pragma unroll
    for (int mt = 0; mt < 4; ++mt)
#pragma unroll
      for (int nt = 0; nt < 2; ++nt) {
        uint2 v;
        v.x = pk_bf16(xm[mt][nt][0], xm[mt][nt][1]);
        v.y = pk_bf16(xm[mt][nt][2], xm[mt][nt][3]);
        *(uint2*)&xsw[(nt * 16 + l4) * XROW + mt * 16 + q * 4] = v;
      }

    // ---- B-frags of x: B[kk=dim=s*32+q*8+j][n=pt=l4] (constant over k) ----
    bf16x8 bx[2][2];
#pragma unroll
    for (int s = 0; s < 2; ++s)
#pragma unroll
      for (int nt = 0; nt < 2; ++nt)
        bx[s][nt] = *(const bf16x8*)&xsw[(nt * 16 + l4) * XROW + s * 32 + q * 8];

    // ---- preload P(k=0) fragments into register buffer 0 ----
    bf16x8 ap[2][4][2];
#pragma unroll
    for (int mt = 0; mt < 4; ++mt)
#pragma unroll
      for (int s = 0; s < 2; ++s)
        ap[0][mt][s] = PswF[(mt * 2 + s) * 64 + lane];

    // ---- pmx GEMM: pmx[cluster][pt] = sum_dim Pmu[cluster][dim]*x[dim][pt] ----
    f32x4 pmx[2][2];
#pragma unroll
    for (int mtc = 0; mtc < 2; ++mtc)
#pragma unroll
      for (int nt = 0; nt < 2; ++nt) {
        f32x4 acc = Z4;
#pragma unroll
        for (int s = 0; s < 2; ++s) {
          bf16x8 a = PmuAF[(mtc * 2 + s) * 64 + lane];
          acc = __builtin_amdgcn_mfma_f32_16x16x32_bf16(a, bx[s][nt], acc, 0, 0, 0);
        }
        pmx[mtc][nt] = acc;
      }
    // spill pmx + e (folded) to wave-private LDS [cluster32][pt32] f32
#pragma unroll
    for (int mtc = 0; mtc < 2; ++mtc)
#pragma unroll
      for (int nt = 0; nt < 2; ++nt)
#pragma unroll
        for (int r = 0; r < 4; ++r)
          pmxw[(mtc * 16 + q * 4 + r) * 32 + nt * 16 + l4] = pmx[mtc][nt][r] + ev[mtc][r];

    f32x4 accY[4][2];
#pragma unroll
    for (int mt = 0; mt < 4; ++mt)
#pragma unroll
      for (int nt = 0; nt < 2; ++nt) accY[mt][nt] = Z4;
    float lsum0 = 0.f, lsum1 = 0.f;

    // ---- k-loop: register-double-buffered P, no barriers ----
#pragma unroll 2
    for (int k = 0; k < KC; ++k) {
      const int cur = k & 1, nxt = cur ^ 1;
      const int kn = (k + 1) & (KC - 1);  // wraps to 0 on last step (harmless)
#pragma unroll
      for (int mt = 0; mt < 4; ++mt)
#pragma unroll
        for (int s = 0; s < 2; ++s)
          ap[nxt][mt][s] = PswF[kn * 512 + (mt * 2 + s) * 64 + lane];

      // y = P x : C[row=dim=mt*16+q*4+r][col=pt=nt*16+l4]
      f32x4 y[4][2];
#pragma unroll
      for (int mt = 0; mt < 4; ++mt)
#pragma unroll
        for (int nt = 0; nt < 2; ++nt) {
          f32x4 acc = Z4;
          acc = __builtin_amdgcn_mfma_f32_16x16x32_bf16(ap[cur][mt][0], bx[0][nt], acc, 0, 0, 0);
          acc = __builtin_amdgcn_mfma_f32_16x16x32_bf16(ap[cur][mt][1], bx[1][nt], acc, 0, 0, 0);
          y[mt][nt] = acc;
        }

      // xy[pt] = x . y : f32x4 accumulators (packed fp32 FMA, chain depth 4)
      f32x4 d0 = xm[0][0] * y[0][0];
      f32x4 d1 = xm[0][1] * y[0][1];
#pragma unroll
      for (int mt = 1; mt < 4; ++mt) {
        d0 += xm[mt][0] * y[mt][0];
        d1 += xm[mt][1] * y[mt][1];
      }
      float xy0 = (d0[0] + d0[1]) + (d0[2] + d0[3]);
      float xy1 = (d1[0] + d1[1]) + (d1[2] + d1[3]);
      xy0 = red32(red16(xy0));
      xy1 = red32(red16(xy1));

      const float pk0 = pmxw[k * 32 + l4];       // includes e_k
      const float pk1 = pmxw[k * 32 + 16 + l4];
      const float w0 = __expf(pk0 - 0.5f * xy0);
      const float w1 = __expf(pk1 - 0.5f * xy1);
      lsum0 += w0;
      lsum1 += w1;
      if (q == 0) {
        wtw[l4 * WT_PITCH + k] = __float2bfloat16(w0);
        wtw[(16 + l4) * WT_PITCH + k] = __float2bfloat16(w1);
      }
      // accY += w * y (packed fp32 FMA)
#pragma unroll
      for (int mt = 0; mt < 4; ++mt) {
        accY[mt][0] += w0 * y[mt][0];
        accY[mt][1] += w1 * y[mt][1];
      }
    }

    // ---- pacc[dim][pt] = sum_k Pmu[k][dim] * wt[k][pt]  (one K=32 GEMM) ----
    bf16x8 wtf[2];
#pragma unroll
    for (int nt = 0; nt < 2; ++nt)
      wtf[nt] = *(const bf16x8*)&wtw[(nt * 16 + l4) * WT_PITCH + q * 8];
    f32x4 pacc[4][2];
#pragma unroll
    for (int mt = 0; mt < 4; ++mt) {
      bf16x8 a = PmuBF[mt * 64 + lane];
      pacc[mt][0] = __builtin_amdgcn_mfma_f32_16x16x32_bf16(a, wtf[0], Z4, 0, 0, 0);
      pacc[mt][1] = __builtin_amdgcn_mfma_f32_16x16x32_bf16(a, wtf[1], Z4, 0, 0, 0);
    }

    // ---- x += (alpha/l) * (pacc - accY) ----
    const float c0 = alpha / lsum0;
    const float c1 = alpha / lsum1;
#pragma unroll
    for (int mt = 0; mt < 4; ++mt) {
      xm[mt][0] += c0 * (pacc[mt][0] - accY[mt][0]);
      xm[mt][1] += c1 * (pacc[mt][1] - accY[mt][1]);
    }
  }  // iterations

  // ---- direct f32x4 stores: 64B-contiguous per quad-row, fully in-bounds ---
#pragma unroll
  for (int mt = 0; mt < 4; ++mt)
#pragma unroll
    for (int nt = 0; nt < 2; ++nt)
      *(f32x4*)&out[(base_pt + nt * 16 + l4) * 64 + mt * 16 + q * 4] = xm[mt][nt];
}

extern "C" void kernel_launch(void* const* d_in, const int* in_sizes, int n_in,
                              void* d_out, int out_size, void* d_ws, size_t ws_size,
                              hipStream_t stream) {
  (void)in_sizes; (void)n_in; (void)out_size; (void)ws_size;
  const float* x = (const float*)d_in[0];
  const float* c = (const float*)d_in[1];
  const float* mu = (const float*)d_in[2];
  const float* A = (const float*)d_in[3];
  const float* alpha = (const float*)d_in[4];
  float* out = (float*)d_out;

  char* ws = (char*)d_ws;
  float* Pmu_g = (float*)(ws);                           // 8192 B
  float* e_g = (float*)(ws + 8192);                      // 128 B (pad to 256)
  __hip_bfloat16* PmuA = (__hip_bfloat16*)(ws + 8448);   // 4096 B
  __hip_bfloat16* PmuB = (__hip_bfloat16*)(ws + 12544);  // 4096 B
  __hip_bfloat16* Psw = (__hip_bfloat16*)(ws + 16640);   // 262144 B

  precompute1<<<32, 256, 0, stream>>>(A, mu, c, Pmu_g, e_g, Psw);
  precompute2<<<1, 256, 0, stream>>>(Pmu_g, PmuA, PmuB);
  denoise_main<<<512, 256, 0, stream>>>(x, e_g, alpha, Psw, PmuA, PmuB, out);
}